// Round 2
// baseline (993.270 us; speedup 1.0000x reference)
//
#include <hip/hip_runtime.h>

#define BATCH 256
#define SEQ   780
#define DIM   1024
#define TOK   195   // MAX_TOKENS
#define MAXHP 14    // Hp = h/4 <= 13, so r in [0, MAXHP) covers all rows + >=1 zero block
#define ROWV  (DIM / 4)   // 256 v4f chunks per token

// native clang vector type — required by __builtin_nontemporal_load/store
typedef float v4f __attribute__((ext_vector_type(4)));

// One block per (b, r): r < Hp -> pooled row r (contiguous read of 2*W2 tokens,
// contiguous write of Wp tokens). r >= Hp -> slice of the contiguous zero region.
__global__ __launch_bounds__(256) void AvgPoolingMerger_90563680403997_kernel(
    const float* __restrict__ hs,        // [B, S, D]
    const int*   __restrict__ grid_thw,  // [B, 3]
    float* __restrict__ out,             // [B, TOK, D]
    float* __restrict__ attn)            // [B, TOK] (written as float 0/1)
{
    const int r = blockIdx.x;   // pooled row candidate [0, MAXHP)
    const int b = blockIdx.y;   // batch index
    const int t = threadIdx.x;  // 256 threads -> one v4f lane of a token

    const int h  = grid_thw[b * 3 + 1];
    const int w  = grid_thw[b * 3 + 2];
    const int W2 = w >> 1;              // pre-pool grid width
    const int Wp = w >> 2;              // pooled grid width
    const int Hp = h >> 2;              // pooled grid height
    const int n_out = Hp * Wp;

    if (r < Hp) {
        // ---- valid pooled row r ----
        // input rows 2r and 2r+1 of the (H2, W2) token grid are one contiguous
        // span of 2*W2 tokens starting at token 2*r*W2.
        const v4f* __restrict__ in0 =
            (const v4f*)hs + ((size_t)b * SEQ + (size_t)(2 * r) * W2) * ROWV;
        const v4f* __restrict__ in1 = in0 + (size_t)W2 * ROWV;  // row 2r+1
        v4f* __restrict__ op =
            (v4f*)out + ((size_t)b * TOK + (size_t)r * Wp) * ROWV;

        int c = 0;
        // unroll 2: 8 independent non-temporal loads in flight per wave
        for (; c + 2 <= Wp; c += 2) {
            const v4f a0 = __builtin_nontemporal_load(in0 + (2 * c    ) * ROWV + t);
            const v4f a1 = __builtin_nontemporal_load(in0 + (2 * c + 1) * ROWV + t);
            const v4f a2 = __builtin_nontemporal_load(in1 + (2 * c    ) * ROWV + t);
            const v4f a3 = __builtin_nontemporal_load(in1 + (2 * c + 1) * ROWV + t);
            const v4f b0 = __builtin_nontemporal_load(in0 + (2 * c + 2) * ROWV + t);
            const v4f b1 = __builtin_nontemporal_load(in0 + (2 * c + 3) * ROWV + t);
            const v4f b2 = __builtin_nontemporal_load(in1 + (2 * c + 2) * ROWV + t);
            const v4f b3 = __builtin_nontemporal_load(in1 + (2 * c + 3) * ROWV + t);
            __builtin_nontemporal_store((a0 + a1 + a2 + a3) * 0.25f,
                                        op + (c    ) * ROWV + t);
            __builtin_nontemporal_store((b0 + b1 + b2 + b3) * 0.25f,
                                        op + (c + 1) * ROWV + t);
        }
        if (c < Wp) {  // odd-Wp tail
            const v4f a0 = __builtin_nontemporal_load(in0 + (2 * c    ) * ROWV + t);
            const v4f a1 = __builtin_nontemporal_load(in0 + (2 * c + 1) * ROWV + t);
            const v4f a2 = __builtin_nontemporal_load(in1 + (2 * c    ) * ROWV + t);
            const v4f a3 = __builtin_nontemporal_load(in1 + (2 * c + 1) * ROWV + t);
            __builtin_nontemporal_store((a0 + a1 + a2 + a3) * 0.25f,
                                        op + c * ROWV + t);
        }
        if (t < Wp) attn[(size_t)b * TOK + (size_t)r * Wp + t] = 1.0f;
    } else {
        // ---- zero region [n_out, TOK): contiguous, split among MAXHP-Hp blocks ----
        const int nb = MAXHP - Hp;          // >= 1 (Hp <= 13)
        const int ib = r - Hp;
        const int nz = TOK - n_out;
        const int j0 = n_out + (nz * ib) / nb;
        const int j1 = n_out + (nz * (ib + 1)) / nb;

        v4f* __restrict__ op = (v4f*)out + (size_t)b * TOK * ROWV;
        const v4f z = {0.f, 0.f, 0.f, 0.f};
        for (int k = j0 * ROWV + t; k < j1 * ROWV; k += 256)
            __builtin_nontemporal_store(z, op + k);

        const int cnt = j1 - j0;            // <= 179 < 256
        if (t < cnt) attn[(size_t)b * TOK + j0 + t] = 0.0f;
    }
}

extern "C" void kernel_launch(void* const* d_in, const int* in_sizes, int n_in,
                              void* d_out, int out_size, void* d_ws, size_t ws_size,
                              hipStream_t stream) {
    const float* hs       = (const float*)d_in[0];  // hidden_states [B,S,D] fp32
    // d_in[1] = attention_mask [B,S] int32 (unused by the computation)
    const int*   grid_thw = (const int*)d_in[2];    // image_grid_thw [B,3] int32

    float* out  = (float*)d_out;                    // [B, TOK, D]
    float* attn = out + (size_t)BATCH * TOK * DIM;  // [B, TOK] as float 0/1

    dim3 grid(MAXHP, BATCH);
    AvgPoolingMerger_90563680403997_kernel<<<grid, 256, 0, stream>>>(hs, grid_thw, out, attn);
}

// Round 3
// 974.832 us; speedup vs baseline: 1.0189x; 1.0189x over previous
//
#include <hip/hip_runtime.h>

#define BATCH 256
#define SEQ   780
#define DIM   1024
#define TOK   195   // MAX_TOKENS
#define MAXHP 14    // Hp = h/4 <= 13, so r in [0, MAXHP) covers all rows + >=1 zero block
#define ROWV  (DIM / 4)   // 256 v4f chunks per token

// native clang vector type — required by __builtin_nontemporal_load/store
typedef float v4f __attribute__((ext_vector_type(4)));

// One block per (b, r): r < Hp -> pooled row r (contiguous read of 2*W2 tokens,
// contiguous write of Wp tokens), software-pipelined with 1-pair lookahead so
// 8 NT loads stay in flight across the store (s_waitcnt vmcnt(8), not drain).
// r >= Hp -> slice of the contiguous zero region.
__global__ __launch_bounds__(256) void AvgPoolingMerger_90563680403997_kernel(
    const float* __restrict__ hs,        // [B, S, D]
    const int*   __restrict__ grid_thw,  // [B, 3]
    float* __restrict__ out,             // [B, TOK, D]
    float* __restrict__ attn)            // [B, TOK] (written as float 0/1)
{
    const int r = blockIdx.x;   // pooled row candidate [0, MAXHP)
    const int b = blockIdx.y;   // batch index
    const int t = threadIdx.x;  // 256 threads -> one v4f lane of a token

    const int h  = grid_thw[b * 3 + 1];
    const int w  = grid_thw[b * 3 + 2];
    const int W2 = w >> 1;              // pre-pool grid width  [8, 26]
    const int Wp = w >> 2;              // pooled grid width    [4, 13]
    const int Hp = h >> 2;              // pooled grid height   [4, 13]
    const int n_out = Hp * Wp;

    if (r < Hp) {
        // input rows 2r, 2r+1 of the (H2, W2) grid = contiguous span at token 2r*W2
        const v4f* __restrict__ in0 =
            (const v4f*)hs + ((size_t)b * SEQ + (size_t)(2 * r) * W2) * ROWV + t;
        const v4f* __restrict__ in1 = in0 + (size_t)W2 * ROWV;  // row 2r+1
        v4f* __restrict__ op =
            (v4f*)out + ((size_t)b * TOK + (size_t)r * Wp) * ROWV + t;

        // token c occupies input tokens 2c, 2c+1 in each of the two rows
        #define LD4(dst0, dst1, dst2, dst3, c)                                   \
            dst0 = __builtin_nontemporal_load(in0 + (2 * (c)    ) * ROWV);       \
            dst1 = __builtin_nontemporal_load(in0 + (2 * (c) + 1) * ROWV);       \
            dst2 = __builtin_nontemporal_load(in1 + (2 * (c)    ) * ROWV);       \
            dst3 = __builtin_nontemporal_load(in1 + (2 * (c) + 1) * ROWV);

        const int Wp2 = Wp & ~1;        // even part, >= 4
        v4f a0, a1, a2, a3, b0, b1, b2, b3;
        v4f c0, c1, c2, c3, d0, d1, d2, d3;

        LD4(a0, a1, a2, a3, 0)          // prologue: tokens 0,1 in flight
        LD4(b0, b1, b2, b3, 1)

        int c = 0;
        for (; c + 2 < Wp2; c += 2) {
            LD4(c0, c1, c2, c3, c + 2)  // prefetch next pair BEFORE the stores:
            LD4(d0, d1, d2, d3, c + 3)  // stores wait vmcnt(8), keep 8 loads live
            __builtin_nontemporal_store((a0 + a1 + a2 + a3) * 0.25f, op + (c    ) * ROWV);
            __builtin_nontemporal_store((b0 + b1 + b2 + b3) * 0.25f, op + (c + 1) * ROWV);
            a0 = c0; a1 = c1; a2 = c2; a3 = c3;
            b0 = d0; b1 = d1; b2 = d2; b3 = d3;
        }
        // last even pair
        __builtin_nontemporal_store((a0 + a1 + a2 + a3) * 0.25f, op + (c    ) * ROWV);
        __builtin_nontemporal_store((b0 + b1 + b2 + b3) * 0.25f, op + (c + 1) * ROWV);
        if (Wp & 1) {                   // odd tail token
            LD4(a0, a1, a2, a3, Wp - 1)
            __builtin_nontemporal_store((a0 + a1 + a2 + a3) * 0.25f, op + (Wp - 1) * ROWV);
        }
        #undef LD4

        if (t < Wp) attn[(size_t)b * TOK + (size_t)r * Wp + t] = 1.0f;
    } else {
        // ---- zero region [n_out, TOK): contiguous, split among MAXHP-Hp blocks ----
        const int nb = MAXHP - Hp;          // >= 1 (Hp <= 13)
        const int ib = r - Hp;
        const int nz = TOK - n_out;
        const int j0 = n_out + (nz * ib) / nb;
        const int j1 = n_out + (nz * (ib + 1)) / nb;

        v4f* __restrict__ op = (v4f*)out + (size_t)b * TOK * ROWV;
        const v4f z = {0.f, 0.f, 0.f, 0.f};
        for (int k = j0 * ROWV + t; k < j1 * ROWV; k += 256)
            __builtin_nontemporal_store(z, op + k);

        const int cnt = j1 - j0;            // <= 179 < 256
        if (t < cnt) attn[(size_t)b * TOK + j0 + t] = 0.0f;
    }
}

extern "C" void kernel_launch(void* const* d_in, const int* in_sizes, int n_in,
                              void* d_out, int out_size, void* d_ws, size_t ws_size,
                              hipStream_t stream) {
    const float* hs       = (const float*)d_in[0];  // hidden_states [B,S,D] fp32
    // d_in[1] = attention_mask [B,S] int32 (unused by the computation)
    const int*   grid_thw = (const int*)d_in[2];    // image_grid_thw [B,3] int32

    float* out  = (float*)d_out;                    // [B, TOK, D]
    float* attn = out + (size_t)BATCH * TOK * DIM;  // [B, TOK] as float 0/1

    dim3 grid(MAXHP, BATCH);
    AvgPoolingMerger_90563680403997_kernel<<<grid, 256, 0, stream>>>(hs, grid_thw, out, attn);
}